// Round 7
// baseline (2376.730 us; speedup 1.0000x reference)
//
#include <hip/hip_runtime.h>
#include <math.h>

#define B_N 256
#define T_N 1024
#define D_N 128
#define H_N 256
#define NSEG 64    // blocks per b; each block covers 16 t-rows

// LDS (shorts): 16-row ping-pong activation buffers + guards + accum.
// 8,736 B/block -> occupancy capped by WAVE SLOTS (8 blocks = 32 waves/CU),
// not LDS/VGPR. Per-wave chain is ~1/4 of the old structure (n-tiles split
// across the 4 waves) -> latency-bound wall time ~ chain/concurrency.
#define SPS 120                   // 112 cols + pad; 16B-unit stride 15 (odd) -> conflict-free
#define SP_OFF  0                 // 16*120 = 1920
#define SQ_OFF  1928              // after 8-short guard
#define ACC_OFF 3856              // after 2nd guard; byte 7712 (16B mult)
#define SMEM_SH 4368              // 8,736 B

typedef __attribute__((ext_vector_type(8))) short short8;   // 8 bf16 = 4 VGPRs
typedef __attribute__((ext_vector_type(4))) float f32x4;

// ws layout (bf16 units): weights in MFMA fragment order; each B-fragment is
// ONE coalesced 1KB global_load_dwordx4 (lane i reads bytes [16i,16i+16)).
//   elem index within layer: (nt*KR + k4)*512 + lane*8 + j
//   holds WT[n = nt*16 + (lane&15)][k = k4*32 + (lane>>4)*8 + j], zero-padded.
#define WXT_OFF 0         // NT=16 KR=4 -> 32768
#define W1T_OFF 32768     // NT=7  KR=4 -> 14336
#define W2T_OFF 47104     // NT=7  KR=4 -> 14336   rows k>=100 ZERO
#define W3T_OFF 61440     // NT=7  KR=4 -> 14336
#define W4T_OFF 75776     // NT=4  KR=4 ->  8192
#define W5T_OFF 83968     // NT=16 KR=2 -> 16384   rows k>=50 zero
#define WT_TOTAL 100352
// done-counters: 256 ints right after the weights in ws (byte off 200,704)

__device__ __forceinline__ float sigmoid_f(float z) {
    return 1.0f / (1.0f + __expf(-z));
}
__device__ __forceinline__ unsigned short f2bf(float f) {   // RNE fp32->bf16
    unsigned u = __float_as_uint(f);
    return (unsigned short)((u + 0x7FFFu + ((u >> 16) & 1u)) >> 16);
}

// ---- prep: fp32 W[K][N] -> bf16 fragment-ordered + zero out[] and cnt[]
__global__ __launch_bounds__(256) void prep_init(
    const float* __restrict__ Wx, const float* __restrict__ W1,
    const float* __restrict__ W2, const float* __restrict__ W3,
    const float* __restrict__ W4, const float* __restrict__ W5,
    short* __restrict__ wt, float* __restrict__ out, int* __restrict__ cnt)
{
    int idx = blockIdx.x * 256 + threadIdx.x;
    // zero out (65792 floats = 16448 float4) + cnt (256 ints)
    if (idx < 16448) {
        const float4 z = {0.f, 0.f, 0.f, 0.f};
        reinterpret_cast<float4*>(out)[idx] = z;
    } else if (idx < 16448 + 256) {
        cnt[idx - 16448] = 0;
    }
    if (idx >= WT_TOTAL) return;
    const float* src; int base, KR, K, N;
    if (idx < W1T_OFF)      { src = Wx; base = WXT_OFF; KR = 4; K = 128; N = 256; }
    else if (idx < W2T_OFF) { src = W1; base = W1T_OFF; KR = 4; K = 128; N = 100; }
    else if (idx < W3T_OFF) { src = W2; base = W2T_OFF; KR = 4; K = 100; N = 100; }
    else if (idx < W4T_OFF) { src = W3; base = W3T_OFF; KR = 4; K = 100; N = 100; }
    else if (idx < W5T_OFF) { src = W4; base = W4T_OFF; KR = 4; K = 100; N =  50; }
    else                    { src = W5; base = W5T_OFF; KR = 2; K =  50; N = 256; }
    int e    = idx - base;
    int j    = e & 7;
    int slot = e >> 3;            // (nt*KR + k4)*64 + lane
    int lane = slot & 63;
    int kk   = slot >> 6;
    int k4   = kk & (KR - 1);
    int nt   = kk / KR;
    int n = nt * 16 + (lane & 15);
    int k = k4 * 32 + (lane >> 4) * 8 + j;
    float v = (k < K && n < N) ? src[(size_t)k * N + n] : 0.0f;
    wt[idx] = (short)f2bf(v);
}

// A-fragment set (K=128) for the block's 16 rows: lane holds A[m=lr][k*32+lq*8+j]
__device__ __forceinline__ void loadA16(const short* __restrict__ base, short8 (&a)[4],
                                        int lr, int lq)
{
    #pragma unroll
    for (int k = 0; k < 4; ++k)
        a[k] = *reinterpret_cast<const short8*>(&base[lr * SPS + k * 32 + lq * 8]);
}

// 7-tile layer split across 4 waves: wave w owns tiles {w, w+4} (wave 3: {3}).
// 8 B-fragment loads issued up front (one latency window), then 8 MFMAs.
// Per-wave live set (a 16 + b0/b1 32 + acc 8) fits the 64-VGPR class.
__device__ __forceinline__ void dense7(const short8 (&a)[4], const short* __restrict__ gW,
                                       const float* __restrict__ bias,
                                       short* __restrict__ dst, int wid, int lr, int lq,
                                       int lane)
{
    const short* gp = gW + lane * 8;
    const bool two = (wid < 3);
    short8 b0[4], b1[4];
    #pragma unroll
    for (int k = 0; k < 4; ++k)
        b0[k] = *reinterpret_cast<const short8*>(gp + (wid * 4 + k) * 512);
    if (two) {
        #pragma unroll
        for (int k = 0; k < 4; ++k)
            b1[k] = *reinterpret_cast<const short8*>(gp + ((wid + 4) * 4 + k) * 512);
    }
    f32x4 acc0 = {0.f, 0.f, 0.f, 0.f};
    #pragma unroll
    for (int k = 0; k < 4; ++k)
        acc0 = __builtin_amdgcn_mfma_f32_16x16x32_bf16(a[k], b0[k], acc0, 0, 0, 0);
    {
        const int n0 = wid * 16;
        const bool valid = (n0 + lr < 100);
        const float bv = valid ? bias[n0 + lr] : 0.0f;
        #pragma unroll
        for (int r = 0; r < 4; ++r) {
            float v = valid ? fmaxf(acc0[r] + bv, 0.0f) : 0.0f;
            dst[(lq * 4 + r) * SPS + n0 + lr] = (short)f2bf(v);
        }
    }
    if (two) {
        f32x4 acc1 = {0.f, 0.f, 0.f, 0.f};
        #pragma unroll
        for (int k = 0; k < 4; ++k)
            acc1 = __builtin_amdgcn_mfma_f32_16x16x32_bf16(a[k], b1[k], acc1, 0, 0, 0);
        const int n0 = (wid + 4) * 16;
        const bool valid = (n0 + lr < 100);
        const float bv = valid ? bias[n0 + lr] : 0.0f;
        #pragma unroll
        for (int r = 0; r < 4; ++r) {
            float v = valid ? fmaxf(acc1[r] + bv, 0.0f) : 0.0f;
            dst[(lq * 4 + r) * SPS + n0 + lr] = (short)f2bf(v);
        }
    }
}

// 4-tile layer (L4, ncap 50): wave w owns tile w.
__device__ __forceinline__ void dense4(const short8 (&a)[4], const short* __restrict__ gW,
                                       const float* __restrict__ bias,
                                       short* __restrict__ dst, int wid, int lr, int lq,
                                       int lane)
{
    const short* gp = gW + lane * 8;
    short8 bf[4];
    #pragma unroll
    for (int k = 0; k < 4; ++k)
        bf[k] = *reinterpret_cast<const short8*>(gp + (wid * 4 + k) * 512);
    f32x4 acc = {0.f, 0.f, 0.f, 0.f};
    #pragma unroll
    for (int k = 0; k < 4; ++k)
        acc = __builtin_amdgcn_mfma_f32_16x16x32_bf16(a[k], bf[k], acc, 0, 0, 0);
    const int n0 = wid * 16;
    const bool valid = (n0 + lr < 50);
    const float bv = valid ? bias[n0 + lr] : 0.0f;
    #pragma unroll
    for (int r = 0; r < 4; ++r) {
        float v = valid ? fmaxf(acc[r] + bv, 0.0f) : 0.0f;
        dst[(lq * 4 + r) * SPS + n0 + lr] = (short)f2bf(v);
    }
}

// Fused MLP + linearized scan + (last block per b) the output head.
//   hidden[b,h] = sum_t gate[t,b,(h - s*(T-1-t)) mod H]
// Grid 16384 = 64 t-segments x 256 batch; block = 4 waves SHARING 16 t-rows,
// n-tiles split across waves (chain/4), 1 barrier per layer. 8 blocks/CU
// (wave-slot cap). Duplicate x/A reads across the 4 waves are same-CU L1 hits.
__global__ __launch_bounds__(256, 4) void srnn_gate_scan(
    const float* __restrict__ x, const short* __restrict__ wt,
    const float* __restrict__ bx, const float* __restrict__ b1,
    const float* __restrict__ b2, const float* __restrict__ b3,
    const float* __restrict__ b4, const float* __restrict__ b5,
    const int* __restrict__ shiftp,
    const float* __restrict__ Wo, const float* __restrict__ bo,
    int* __restrict__ cnt,
    float* __restrict__ out)   // out[0..255]=output, out[256..]=hidden
{
    __shared__ __align__(16) short smem[SMEM_SH];
    short* sP = smem + SP_OFF;
    short* sQ = smem + SQ_OFF;
    float* accum = reinterpret_cast<float*>(smem + ACC_OFF);

    const int tid  = threadIdx.x;
    const int b    = blockIdx.x & 255;
    const int seg  = blockIdx.x >> 8;      // 0..63
    const int lane = tid & 63;
    const int wid  = tid >> 6;
    const int lr = lane & 15;              // A m-index / B n-index / C-D col
    const int lq = lane >> 4;              // quad; C/D row = lq*4+r
    const int s  = *shiftp;
    const int tw0 = seg * 16;              // block's first t

    // zero ALL of LDS (act pads + guards finite; accum zeroed for atomics)
    {
        const float4 z = {0.f, 0.f, 0.f, 0.f};
        float4* dst = reinterpret_cast<float4*>(smem);
        #pragma unroll
        for (int i = 0; i < 3; ++i) {
            int sl = tid + i * 256;
            if (sl < SMEM_SH / 8) dst[sl] = z;
        }
    }

    // x A-fragments from global (row = lr per lane); all 4 waves read the
    // same addresses -> L1 broadcast. f2bf in regs.
    short8 ax4[4];
    {
        const float* xr = x + ((size_t)b * T_N + tw0 + lr) * D_N;
        #pragma unroll
        for (int k = 0; k < 4; ++k) {
            const float4 v0 = *reinterpret_cast<const float4*>(&xr[k * 32 + lq * 8]);
            const float4 v1 = *reinterpret_cast<const float4*>(&xr[k * 32 + lq * 8 + 4]);
            short8 t;
            t[0] = (short)f2bf(v0.x); t[1] = (short)f2bf(v0.y);
            t[2] = (short)f2bf(v0.z); t[3] = (short)f2bf(v0.w);
            t[4] = (short)f2bf(v1.x); t[5] = (short)f2bf(v1.y);
            t[6] = (short)f2bf(v1.z); t[7] = (short)f2bf(v1.w);
            ax4[k] = t;
        }
    }
    __syncthreads();                       // zero-init visible to all waves

    // ---- MLP chain: one barrier per layer (write bufA -> barrier -> read
    // bufA, write bufB). Reads complete before each wave's barrier (compiler
    // waitcnt before MFMA use), so the next layer's writes can't race them.
    short8 aL[4];
    dense7(ax4, wt + W1T_OFF, b1, sP, wid, lr, lq, lane);
    __syncthreads();
    loadA16(sP, aL, lr, lq);
    dense7(aL, wt + W2T_OFF, b2, sQ, wid, lr, lq, lane);
    __syncthreads();
    loadA16(sQ, aL, lr, lq);
    dense7(aL, wt + W3T_OFF, b3, sP, wid, lr, lq, lane);
    __syncthreads();
    loadA16(sP, aL, lr, lq);
    dense4(aL, wt + W4T_OFF, b4, sQ, wid, lr, lq, lane);
    __syncthreads();

    // L4 output as K=64 A-fragments for L5 (cols 50..63 zero from ncap)
    short8 c0 = *reinterpret_cast<const short8*>(&sQ[lr * SPS + 0 + lq * 8]);
    short8 c1 = *reinterpret_cast<const short8*>(&sQ[lr * SPS + 32 + lq * 8]);

    // ---- tail: Lx (A=ax4) + L5 (A=c0/c1) + gate + scatter; wave owns 4
    // n-tiles (iterations independent -> compiler overlaps within budget)
    const short* gpx = wt + WXT_OFF + lane * 8;
    const short* gp5 = wt + W5T_OFF + lane * 8;
    const int tbase = T_N - 1 - tw0;
    #pragma unroll
    for (int i = 0; i < 4; ++i) {
        const int ntl = wid * 4 + i;
        const int n0 = ntl * 16;
        short8 wf[4], vf[2];
        #pragma unroll
        for (int k = 0; k < 4; ++k)
            wf[k] = *reinterpret_cast<const short8*>(gpx + (ntl * 4 + k) * 512);
        vf[0] = *reinterpret_cast<const short8*>(gp5 + (ntl * 2 + 0) * 512);
        vf[1] = *reinterpret_cast<const short8*>(gp5 + (ntl * 2 + 1) * 512);
        f32x4 e = {0.f, 0.f, 0.f, 0.f}, o = {0.f, 0.f, 0.f, 0.f};
        e = __builtin_amdgcn_mfma_f32_16x16x32_bf16(ax4[0], wf[0], e, 0, 0, 0);
        o = __builtin_amdgcn_mfma_f32_16x16x32_bf16(ax4[1], wf[1], o, 0, 0, 0);
        e = __builtin_amdgcn_mfma_f32_16x16x32_bf16(ax4[2], wf[2], e, 0, 0, 0);
        o = __builtin_amdgcn_mfma_f32_16x16x32_bf16(ax4[3], wf[3], o, 0, 0, 0);
        f32x4 a5v = {0.f, 0.f, 0.f, 0.f};
        a5v = __builtin_amdgcn_mfma_f32_16x16x32_bf16(c0, vf[0], a5v, 0, 0, 0);
        a5v = __builtin_amdgcn_mfma_f32_16x16x32_bf16(c1, vf[1], a5v, 0, 0, 0);
        const float bxv = bx[n0 + lr];
        const float b5v = b5[n0 + lr];
        #pragma unroll
        for (int r = 0; r < 4; ++r) {
            const int toff = lq * 4 + r;
            // sigmoid(a)*sigmoid(b) = 1/((1+e^-a)(1+e^-b)): one rcp
            const float ea = __expf(-(a5v[r] + b5v));
            const float eb = __expf(-(e[r] + o[r] + bxv));
            const float g = 1.0f / ((1.0f + ea) * (1.0f + eb));
            // (unsigned)v & 255 == v mod 256 (2^32 % 256 == 0)
            const int h = (int)(((unsigned)(n0 + lr + s * (tbase - toff))) & 255u);
            atomicAdd(&accum[h], g);   // per-t the h-map is a bijection
        }
    }
    __syncthreads();

    // flush partial hidden (64 segment-blocks per b -> global atomic)
    atomicAdd(&out[256 + b * 256 + tid], accum[tid]);
    __threadfence();                       // release our hidden adds
    __syncthreads();

    // last block for this b computes output[b] = sigmoid(hidden . Wo + bo)
    int* flag = reinterpret_cast<int*>(accum);
    if (tid == 0) {
        const int old = atomicAdd(&cnt[b], 1);       // device-scope RMW
        __threadfence();                              // acquire
        flag[0] = (old == NSEG - 1) ? 1 : 0;
    }
    __syncthreads();
    if (!flag[0]) return;

    const float hv = __hip_atomic_load(&out[256 + b * 256 + tid],
                                       __ATOMIC_RELAXED, __HIP_MEMORY_SCOPE_AGENT);
    const float pv = hv * Wo[tid];
    __syncthreads();                       // flag read done before accum reuse
    accum[tid] = pv;
    __syncthreads();
    #pragma unroll
    for (int off = 128; off > 0; off >>= 1) {
        if (tid < off) accum[tid] += accum[tid + off];
        __syncthreads();
    }
    if (tid == 0) out[b] = sigmoid_f(accum[0] + bo[0]);
}

extern "C" void kernel_launch(void* const* d_in, const int* in_sizes, int n_in,
                              void* d_out, int out_size, void* d_ws, size_t ws_size,
                              hipStream_t stream)
{
    const float* x  = (const float*)d_in[0];
    const float* Wx = (const float*)d_in[1];
    const float* bx = (const float*)d_in[2];
    const float* W1 = (const float*)d_in[3];
    const float* b1 = (const float*)d_in[4];
    const float* W2 = (const float*)d_in[5];
    const float* b2 = (const float*)d_in[6];
    const float* W3 = (const float*)d_in[7];
    const float* b3 = (const float*)d_in[8];
    const float* W4 = (const float*)d_in[9];
    const float* b4 = (const float*)d_in[10];
    const float* W5 = (const float*)d_in[11];
    const float* b5 = (const float*)d_in[12];
    const float* Wo = (const float*)d_in[13];
    const float* bo = (const float*)d_in[14];
    const int* shiftp = (const int*)d_in[15];
    float* out = (float*)d_out;
    short* wt  = (short*)d_ws;                       // 200,704 B: bf16 fragment-ordered weights
    int* cnt   = (int*)((char*)d_ws + WT_TOTAL * 2); // 256 done-counters (1 KB)

    // prep zeroes out[] and cnt[] -> no hipMemsetAsync dispatch needed
    prep_init<<<dim3((WT_TOTAL + 255) / 256), dim3(256), 0, stream>>>(
        Wx, W1, W2, W3, W4, W5, wt, out, cnt);
    srnn_gate_scan<<<dim3(16384), dim3(256), 0, stream>>>(
        x, wt, bx, b1, b2, b3, b4, b5, shiftp, Wo, bo, cnt, out);
}

// Round 8
// 874.848 us; speedup vs baseline: 2.7167x; 2.7167x over previous
//
#include <hip/hip_runtime.h>
#include <math.h>

#define B_N 256
#define T_N 1024
#define D_N 128
#define H_N 256
#define NSEG 16    // t-segments per b; each block covers 64 t

// LDS (shorts): sP/sQ ping-pong activations (64 rows x SPS each), 8-short
// guard (zeroed; catches last-row K-overrun b128 reads), accum floats.
#define SPS 120                   // 112 cols + pad; 16B-unit stride 15 (odd) -> conflict-free
#define SP_OFF  0                 // 64*120 = 7680
#define SQ_OFF  7680              // 7680
#define ACC_OFF 15368             // after guard; byte 30736 (16B mult)
#define SMEM_SH 15880             // 31,760 B

typedef __attribute__((ext_vector_type(8))) short short8;   // 8 bf16 = 4 VGPRs
typedef __attribute__((ext_vector_type(4))) float f32x4;

// ws layout (bf16 units): weights in MFMA fragment order; each B-fragment is
// ONE coalesced 1KB global_load_dwordx4 (lane i reads bytes [16i,16i+16)).
//   elem index within layer: (nt*KR + k4)*512 + lane*8 + j
//   holds WT[n = nt*16 + (lane&15)][k = k4*32 + (lane>>4)*8 + j], zero-padded.
// W1..W4 are CONSECUTIVE with stride 14336 -> one rolled layer loop.
#define WXT_OFF 0         // NT=16 KR=4 -> 32768
#define W1T_OFF 32768     // NT=7  KR=4 -> 14336
#define W2T_OFF 47104     // NT=7  KR=4 -> 14336   rows k>=100 ZERO
#define W3T_OFF 61440     // NT=7  KR=4 -> 14336
#define W4T_OFF 75776     // NT=4  KR=4 ->  8192   rows k>=100 zero, n>=50 zero
#define W5T_OFF 83968     // NT=16 KR=2 -> 16384   rows k>=50 zero
#define WT_TOTAL 100352
// done-counters: 256 ints right after the weights in ws (byte off 200,704)

__device__ __forceinline__ float sigmoid_f(float z) {
    return 1.0f / (1.0f + __expf(-z));
}
__device__ __forceinline__ unsigned short f2bf(float f) {   // RNE fp32->bf16
    unsigned u = __float_as_uint(f);
    return (unsigned short)((u + 0x7FFFu + ((u >> 16) & 1u)) >> 16);
}

// ---- prep: fp32 W[K][N] -> bf16 fragment-ordered + zero out[] and cnt[]
__global__ __launch_bounds__(256) void prep_init(
    const float* __restrict__ Wx, const float* __restrict__ W1,
    const float* __restrict__ W2, const float* __restrict__ W3,
    const float* __restrict__ W4, const float* __restrict__ W5,
    short* __restrict__ wt, float* __restrict__ out, int* __restrict__ cnt)
{
    int idx = blockIdx.x * 256 + threadIdx.x;
    // zero out (65792 floats = 16448 float4) + cnt (256 ints)
    if (idx < 16448) {
        const float4 z = {0.f, 0.f, 0.f, 0.f};
        reinterpret_cast<float4*>(out)[idx] = z;
    } else if (idx < 16448 + 256) {
        cnt[idx - 16448] = 0;
    }
    if (idx >= WT_TOTAL) return;
    const float* src; int base, KR, K, N;
    if (idx < W1T_OFF)      { src = Wx; base = WXT_OFF; KR = 4; K = 128; N = 256; }
    else if (idx < W2T_OFF) { src = W1; base = W1T_OFF; KR = 4; K = 128; N = 100; }
    else if (idx < W3T_OFF) { src = W2; base = W2T_OFF; KR = 4; K = 100; N = 100; }
    else if (idx < W4T_OFF) { src = W3; base = W3T_OFF; KR = 4; K = 100; N = 100; }
    else if (idx < W5T_OFF) { src = W4; base = W4T_OFF; KR = 4; K = 100; N =  50; }
    else                    { src = W5; base = W5T_OFF; KR = 2; K =  50; N = 256; }
    int e    = idx - base;
    int j    = e & 7;
    int slot = e >> 3;            // (nt*KR + k4)*64 + lane
    int lane = slot & 63;
    int kk   = slot >> 6;
    int k4   = kk & (KR - 1);
    int nt   = kk / KR;
    int n = nt * 16 + (lane & 15);
    int k = k4 * 32 + (lane >> 4) * 8 + j;
    float v = (k < K && n < N) ? src[(size_t)k * N + n] : 0.0f;
    wt[idx] = (short)f2bf(v);
}

// Fused MLP + linearized scan + (last block per b) the output head.
//   hidden[b,h] = sum_t gate[t,b,(h - s*(T-1-t)) mod H]
// Grid 4096 = 16 t-segments x 256 batch; block = 4 waves x 16 t-rows each.
// CODE-COMPACT build: all seven prior rounds kept constant VALU/MFMA-seconds
// while stalls scaled with (code bytes x wave count) -> I-cache thrash theory
// (fully-unrolled bodies were 60-80KB vs 32KB I-cache; R7: same code, 1/4
// work/block, 4x blocks = 4x time). Layers/tiles/tail are ROLLED loops
// (#pragma unroll 1); fragment arrays keep static k-indices (no scratch).
__global__ __launch_bounds__(256, 4) void srnn_gate_scan(
    const float* __restrict__ x, const short* __restrict__ wt,
    const float* __restrict__ bx, const float* __restrict__ b1,
    const float* __restrict__ b2, const float* __restrict__ b3,
    const float* __restrict__ b4, const float* __restrict__ b5,
    const int* __restrict__ shiftp,
    const float* __restrict__ Wo, const float* __restrict__ bo,
    int* __restrict__ cnt,
    float* __restrict__ out)   // out[0..255]=output, out[256..]=hidden
{
    __shared__ __align__(16) short smem[SMEM_SH];
    short* sP = smem + SP_OFF;
    short* sQ = smem + SQ_OFF;
    float* accum = reinterpret_cast<float*>(smem + ACC_OFF);

    const int tid  = threadIdx.x;
    const int b    = blockIdx.x & 255;
    const int seg  = blockIdx.x >> 8;      // 0..15
    const int lane = tid & 63;
    const int mbase = (tid >> 6) * 16;     // wave's row base in LDS
    const int lr = lane & 15;              // A m-index / B n-index / C-D col
    const int lq = lane >> 4;              // quad; C/D row = lq*4+r
    const int s  = *shiftp;
    const int tw0 = seg * 64 + mbase;      // t of this wave's row 0

    // zero ALL of LDS (act pads + guard finite; accum zeroed for atomics)
    {
        const float4 z = {0.f, 0.f, 0.f, 0.f};
        float4* dst = reinterpret_cast<float4*>(smem);
        #pragma unroll
        for (int i = 0; i < 8; ++i) {
            int sl = tid + i * 256;
            if (sl < SMEM_SH / 8) dst[sl] = z;
        }
    }

    // x A-fragments straight from global (row = lr per lane), f2bf in regs
    short8 ax4[4];
    {
        const float* xr = x + ((size_t)b * T_N + tw0 + lr) * D_N;
        #pragma unroll
        for (int k = 0; k < 4; ++k) {
            const float4 v0 = *reinterpret_cast<const float4*>(&xr[k * 32 + lq * 8]);
            const float4 v1 = *reinterpret_cast<const float4*>(&xr[k * 32 + lq * 8 + 4]);
            short8 t;
            t[0] = (short)f2bf(v0.x); t[1] = (short)f2bf(v0.y);
            t[2] = (short)f2bf(v0.z); t[3] = (short)f2bf(v0.w);
            t[4] = (short)f2bf(v1.x); t[5] = (short)f2bf(v1.y);
            t[6] = (short)f2bf(v1.z); t[7] = (short)f2bf(v1.w);
            ax4[k] = t;
        }
    }
    __syncthreads();                       // zero-init visible to all waves

    // ---- MLP chain: ONE rolled layer loop (L1..L4), zero barriers.
    // Wave-private rows + ping-pong (dst alternates sP,sQ,sP,sQ); same-wave
    // DS ops are in-order, reads land in regs before the next layer's writes.
    short8 aIn[4];
    #pragma unroll
    for (int k = 0; k < 4; ++k) aIn[k] = ax4[k];
    #pragma unroll 1
    for (int L = 0; L < 4; ++L) {
        const short* gp = wt + W1T_OFF + L * 14336 + lane * 8;
        const float* bias = (L == 0) ? b1 : (L == 1) ? b2 : (L == 2) ? b3 : b4;
        const int NT   = (L < 3) ? 7 : 4;
        const int ncap = (L < 3) ? 100 : 50;
        short* dst = (L & 1) ? sQ : sP;
        #pragma unroll 1
        for (int nt = 0; nt < NT; ++nt) {
            const short8 b0 = *reinterpret_cast<const short8*>(gp + (nt * 4 + 0) * 512);
            const short8 b1f = *reinterpret_cast<const short8*>(gp + (nt * 4 + 1) * 512);
            const short8 b2f = *reinterpret_cast<const short8*>(gp + (nt * 4 + 2) * 512);
            const short8 b3f = *reinterpret_cast<const short8*>(gp + (nt * 4 + 3) * 512);
            f32x4 acc = {0.f, 0.f, 0.f, 0.f};
            acc = __builtin_amdgcn_mfma_f32_16x16x32_bf16(aIn[0], b0, acc, 0, 0, 0);
            acc = __builtin_amdgcn_mfma_f32_16x16x32_bf16(aIn[1], b1f, acc, 0, 0, 0);
            acc = __builtin_amdgcn_mfma_f32_16x16x32_bf16(aIn[2], b2f, acc, 0, 0, 0);
            acc = __builtin_amdgcn_mfma_f32_16x16x32_bf16(aIn[3], b3f, acc, 0, 0, 0);
            const int n0 = nt * 16;
            const bool valid = (n0 + lr < ncap);
            const float bv = valid ? bias[n0 + lr] : 0.0f;
            #pragma unroll
            for (int r = 0; r < 4; ++r) {
                float v = valid ? fmaxf(acc[r] + bv, 0.0f) : 0.0f;
                dst[(mbase + lq * 4 + r) * SPS + n0 + lr] = (short)f2bf(v);
            }
        }
        // next layer's A from this layer's output (K slots >= ncap are zero)
        #pragma unroll
        for (int k = 0; k < 4; ++k)
            aIn[k] = *reinterpret_cast<const short8*>(&dst[(mbase + lr) * SPS + k * 32 + lq * 8]);
    }
    // after L4: aIn[0] = cols 0..31 slice, aIn[1] = cols 32..63 -> the K=64
    // L5 A-fragments (cols 50..63 zero from ncap clamp).

    // ---- tail: rolled 16-tile loop. Lx (A=ax4, chained) + L5 (A=aIn[0..1])
    // + fused gate + scatter.
    const short* gx = wt + WXT_OFF + lane * 8;
    const short* g5 = wt + W5T_OFF + lane * 8;
    const int tbase = T_N - 1 - tw0;
    #pragma unroll 1
    for (int ntl = 0; ntl < 16; ++ntl) {
        const short8 w0 = *reinterpret_cast<const short8*>(gx + (ntl * 4 + 0) * 512);
        const short8 w1 = *reinterpret_cast<const short8*>(gx + (ntl * 4 + 1) * 512);
        const short8 w2 = *reinterpret_cast<const short8*>(gx + (ntl * 4 + 2) * 512);
        const short8 w3 = *reinterpret_cast<const short8*>(gx + (ntl * 4 + 3) * 512);
        const short8 v0 = *reinterpret_cast<const short8*>(g5 + (ntl * 2 + 0) * 512);
        const short8 v1 = *reinterpret_cast<const short8*>(g5 + (ntl * 2 + 1) * 512);
        f32x4 e = {0.f, 0.f, 0.f, 0.f};
        e = __builtin_amdgcn_mfma_f32_16x16x32_bf16(ax4[0], w0, e, 0, 0, 0);
        e = __builtin_amdgcn_mfma_f32_16x16x32_bf16(ax4[1], w1, e, 0, 0, 0);
        e = __builtin_amdgcn_mfma_f32_16x16x32_bf16(ax4[2], w2, e, 0, 0, 0);
        e = __builtin_amdgcn_mfma_f32_16x16x32_bf16(ax4[3], w3, e, 0, 0, 0);
        f32x4 a5 = {0.f, 0.f, 0.f, 0.f};
        a5 = __builtin_amdgcn_mfma_f32_16x16x32_bf16(aIn[0], v0, a5, 0, 0, 0);
        a5 = __builtin_amdgcn_mfma_f32_16x16x32_bf16(aIn[1], v1, a5, 0, 0, 0);
        const int n0 = ntl * 16;
        const float bxv = bx[n0 + lr];
        const float b5v = b5[n0 + lr];
        #pragma unroll
        for (int r = 0; r < 4; ++r) {
            const int toff = lq * 4 + r;
            // sigmoid(a)*sigmoid(b) = 1/((1+e^-a)(1+e^-b)): one rcp
            const float ea = __expf(-(a5[r] + b5v));
            const float eb = __expf(-(e[r] + bxv));
            const float g = 1.0f / ((1.0f + ea) * (1.0f + eb));
            // (unsigned)v & 255 == v mod 256 (2^32 % 256 == 0)
            const int h = (int)(((unsigned)(n0 + lr + s * (tbase - toff))) & 255u);
            atomicAdd(&accum[h], g);   // per-t the h-map is a bijection
        }
    }
    __syncthreads();

    // flush partial hidden (16 segment-blocks per b -> global atomic)
    atomicAdd(&out[256 + b * 256 + tid], accum[tid]);
    __threadfence();                       // release our hidden adds
    __syncthreads();

    // last block for this b computes output[b] = sigmoid(hidden . Wo + bo)
    int* flag = reinterpret_cast<int*>(accum);
    if (tid == 0) {
        const int old = atomicAdd(&cnt[b], 1);       // device-scope RMW
        __threadfence();                              // acquire
        flag[0] = (old == NSEG - 1) ? 1 : 0;
    }
    __syncthreads();
    if (!flag[0]) return;

    const float hv = __hip_atomic_load(&out[256 + b * 256 + tid],
                                       __ATOMIC_RELAXED, __HIP_MEMORY_SCOPE_AGENT);
    const float pv = hv * Wo[tid];
    __syncthreads();                       // flag read done before accum reuse
    accum[tid] = pv;
    __syncthreads();
    #pragma unroll
    for (int off = 128; off > 0; off >>= 1) {
        if (tid < off) accum[tid] += accum[tid + off];
        __syncthreads();
    }
    if (tid == 0) out[b] = sigmoid_f(accum[0] + bo[0]);
}

extern "C" void kernel_launch(void* const* d_in, const int* in_sizes, int n_in,
                              void* d_out, int out_size, void* d_ws, size_t ws_size,
                              hipStream_t stream)
{
    const float* x  = (const float*)d_in[0];
    const float* Wx = (const float*)d_in[1];
    const float* bx = (const float*)d_in[2];
    const float* W1 = (const float*)d_in[3];
    const float* b1 = (const float*)d_in[4];
    const float* W2 = (const float*)d_in[5];
    const float* b2 = (const float*)d_in[6];
    const float* W3 = (const float*)d_in[7];
    const float* b3 = (const float*)d_in[8];
    const float* W4 = (const float*)d_in[9];
    const float* b4 = (const float*)d_in[10];
    const float* W5 = (const float*)d_in[11];
    const float* b5 = (const float*)d_in[12];
    const float* Wo = (const float*)d_in[13];
    const float* bo = (const float*)d_in[14];
    const int* shiftp = (const int*)d_in[15];
    float* out = (float*)d_out;
    short* wt  = (short*)d_ws;                       // 200,704 B: bf16 fragment-ordered weights
    int* cnt   = (int*)((char*)d_ws + WT_TOTAL * 2); // 256 done-counters (1 KB)

    // prep zeroes out[] and cnt[] -> no hipMemsetAsync dispatch needed
    prep_init<<<dim3((WT_TOTAL + 255) / 256), dim3(256), 0, stream>>>(
        Wx, W1, W2, W3, W4, W5, wt, out, cnt);
    srnn_gate_scan<<<dim3(4096), dim3(256), 0, stream>>>(
        x, wt, bx, b1, b2, b3, b4, b5, shiftp, Wo, bo, cnt, out);
}